// Round 5
// baseline (687.646 us; speedup 1.0000x reference)
//
#include <hip/hip_runtime.h>

#define N_NODES_C 100000
#define N_EDGES_C 1600000
#define IN_F 64
#define OUT_F 64
#define NK 4
#define SCAN_BLK 256
#define NBLK ((N_NODES_C + SCAN_BLK - 1) / SCAN_BLK)   // 391
#define EBLK (N_EDGES_C / 256)                         // 6250 exact
#define PB 6250                                        // proj blocks (even)
#define NTILES (N_NODES_C / 4)                         // 25000

__device__ __forceinline__ unsigned int f2bf(float x) {
    unsigned int u = __float_as_uint(x);
    return (u + 0x7fffu + ((u >> 16) & 1u)) >> 16;
}
__device__ __forceinline__ float bflo(unsigned int u) { return __uint_as_float(u << 16); }
__device__ __forceinline__ float bfhi(unsigned int u) { return __uint_as_float(u & 0xffff0000u); }

// ---------------------------------------------------------------------------
// fused1: edge blocks [0,EBLK): histogram + gaussian weights (coalesced by e)
//         proj blocks [EBLK, EBLK+PB): h[n][col] bf16, col=(o*4+k)
// proj thread: col = (t>>1) + 128*(pb&1), half = t&1 holds 32 W floats.
// ---------------------------------------------------------------------------
__global__ __launch_bounds__(256, 4) void fused1_kernel(
    const int* __restrict__ src, const int* __restrict__ dst,
    const float* __restrict__ pseudo, const float* __restrict__ mu,
    const float* __restrict__ inv_sigma, int* __restrict__ cnt,
    uint2* __restrict__ g8,
    const float* __restrict__ feat, const float* __restrict__ W,
    unsigned short* __restrict__ hb)
{
    if (blockIdx.x < EBLK) {
        const int e = blockIdx.x * 256 + threadIdx.x;
        if (e >= N_EDGES_C) return;
        atomicAdd(&cnt[dst[e]], 1);
        const float p0 = pseudo[(size_t)e * 3 + 0];
        const float p1 = pseudo[(size_t)e * 3 + 1];
        const float p2 = pseudo[(size_t)e * 3 + 2];
        float g[NK];
        #pragma unroll
        for (int k = 0; k < NK; ++k) {
            const float d0 = p0 - mu[k*3+0], d1 = p1 - mu[k*3+1], d2 = p2 - mu[k*3+2];
            const float s0 = inv_sigma[k*3+0], s1 = inv_sigma[k*3+1], s2 = inv_sigma[k*3+2];
            const float ex = -0.5f * (d0*d0*s0*s0 + d1*d1*s1*s1 + d2*d2*s2*s2);
            g[k] = __expf(ex);
        }
        uint2 r;
        r.x = f2bf(g[0]) | (f2bf(g[1]) << 16);
        r.y = f2bf(g[2]) | (f2bf(g[3]) << 16);
        g8[e] = r;
    } else {
        const int pb = (int)blockIdx.x - EBLK;
        const int t = threadIdx.x;
        const int col = (t >> 1) + 128 * (pb & 1);
        const int h = t & 1;
        const int row = (col & 3) * 64 + (col >> 2);   // W_fc row for this col
        float4 wv[8];
        {
            const float4* W4 = reinterpret_cast<const float4*>(W + (size_t)row * IN_F + h * 32);
            #pragma unroll
            for (int i = 0; i < 8; ++i) wv[i] = W4[i];
        }
        for (int q = pb >> 1; q < NTILES; q += PB / 2) {
            const int n0 = q << 2;
            const float4* F = reinterpret_cast<const float4*>(feat + (size_t)n0 * IN_F + h * 32);
            float a0 = 0.f, a1 = 0.f, a2 = 0.f, a3 = 0.f;
            #pragma unroll
            for (int i0 = 0; i0 < 8; ++i0) {
                const float4 w = wv[i0];
                const float4 f0 = F[i0];
                const float4 f1 = F[i0 + 16];
                const float4 f2 = F[i0 + 32];
                const float4 f3 = F[i0 + 48];
                a0 = fmaf(f0.x,w.x, fmaf(f0.y,w.y, fmaf(f0.z,w.z, fmaf(f0.w,w.w, a0))));
                a1 = fmaf(f1.x,w.x, fmaf(f1.y,w.y, fmaf(f1.z,w.z, fmaf(f1.w,w.w, a1))));
                a2 = fmaf(f2.x,w.x, fmaf(f2.y,w.y, fmaf(f2.z,w.z, fmaf(f2.w,w.w, a2))));
                a3 = fmaf(f3.x,w.x, fmaf(f3.y,w.y, fmaf(f3.z,w.z, fmaf(f3.w,w.w, a3))));
            }
            // combine K-halves (partner lane differs only in h)
            a0 += __shfl_xor(a0, 1, 64);
            a1 += __shfl_xor(a1, 1, 64);
            a2 += __shfl_xor(a2, 1, 64);
            a3 += __shfl_xor(a3, 1, 64);
            // each half stores 2 nodes
            const int na = h * 2;
            const float va = (h == 0) ? a0 : a2;
            const float vb = (h == 0) ? a1 : a3;
            hb[(size_t)(n0 + na + 0) * 256 + col] = (unsigned short)f2bf(va);
            hb[(size_t)(n0 + na + 1) * 256 + col] = (unsigned short)f2bf(vb);
        }
    }
}

// ---------------------------------------------------------------------------
// scan1: per-block sums of cnt
// ---------------------------------------------------------------------------
__global__ __launch_bounds__(256) void scan1_kernel(
    const int* __restrict__ cnt, int* __restrict__ bsum)
{
    __shared__ int s[SCAN_BLK];
    int i = blockIdx.x * SCAN_BLK + threadIdx.x;
    int v = (i < N_NODES_C) ? cnt[i] : 0;
    s[threadIdx.x] = v; __syncthreads();
    for (int off = SCAN_BLK / 2; off > 0; off >>= 1) {
        if (threadIdx.x < off) s[threadIdx.x] += s[threadIdx.x + off];
        __syncthreads();
    }
    if (threadIdx.x == 0) bsum[blockIdx.x] = s[0];
}

// ---------------------------------------------------------------------------
// scan23: block-prefix over bsum + local exclusive scan -> row_start, cursor
// ---------------------------------------------------------------------------
__global__ __launch_bounds__(256) void scan23_kernel(
    const int* __restrict__ cnt, const int* __restrict__ bsum,
    int* __restrict__ row_start, int* __restrict__ cursor)
{
    __shared__ int pre[SCAN_BLK];
    __shared__ int s[SCAN_BLK];
    const int t = threadIdx.x;
    int p = 0;
    for (int i = t; i < (int)blockIdx.x; i += SCAN_BLK) p += bsum[i];
    pre[t] = p; __syncthreads();
    for (int off = SCAN_BLK / 2; off > 0; off >>= 1) {
        if (t < off) pre[t] += pre[t + off];
        __syncthreads();
    }
    const int boff = pre[0];
    const int i = blockIdx.x * SCAN_BLK + t;
    int v = (i < N_NODES_C) ? cnt[i] : 0;
    s[t] = v; __syncthreads();
    for (int off = 1; off < SCAN_BLK; off <<= 1) {
        int x = (t >= off) ? s[t - off] : 0;
        __syncthreads();
        s[t] += x;
        __syncthreads();
    }
    if (i < N_NODES_C) {
        int ex = s[t] - v + boff;
        row_start[i] = ex;
        cursor[i] = ex;
        if (i == N_NODES_C - 1) row_start[N_NODES_C] = ex + v;
    }
}

// ---------------------------------------------------------------------------
// scatter: coalesced reads, atomic pos, one 16B scattered record store
// ---------------------------------------------------------------------------
__global__ __launch_bounds__(256) void scatter_kernel(
    const int* __restrict__ src, const int* __restrict__ dst,
    const uint2* __restrict__ g8, int* __restrict__ cursor,
    uint4* __restrict__ rec)
{
    const int e = blockIdx.x * 256 + threadIdx.x;
    if (e >= N_EDGES_C) return;
    const int d = dst[e];
    const int s = src[e];
    const uint2 g = g8[e];
    const int pos = atomicAdd(&cursor[d], 1);
    uint4 r; r.x = (unsigned int)s; r.y = g.x; r.z = g.y; r.w = 0u;
    rec[pos] = r;
}

// ---------------------------------------------------------------------------
// gather: one wave per dst node, lane = output feature, unroll x4 for MLP.
// ---------------------------------------------------------------------------
__global__ __launch_bounds__(256) void gather_kernel(
    const int* __restrict__ row_start, const uint4* __restrict__ rec,
    const unsigned short* __restrict__ hb,
    const float* __restrict__ feat, const float* __restrict__ bias,
    float* __restrict__ out, int n_nodes)
{
    const int lane = threadIdx.x & 63;
    const int v = (blockIdx.x * 256 + threadIdx.x) >> 6;
    if (v >= n_nodes) return;
    const int r0 = row_start[v];
    const int r1 = row_start[v + 1];
    float acc = 0.f;
    int j = r0;
    for (; j + 4 <= r1; j += 4) {
        const uint4 ra = rec[j+0];
        const uint4 rb = rec[j+1];
        const uint4 rc = rec[j+2];
        const uint4 rd = rec[j+3];
        const uint2 ha = *(const uint2*)(hb + (size_t)ra.x * 256 + lane * 4);
        const uint2 hbv= *(const uint2*)(hb + (size_t)rb.x * 256 + lane * 4);
        const uint2 hc = *(const uint2*)(hb + (size_t)rc.x * 256 + lane * 4);
        const uint2 hd = *(const uint2*)(hb + (size_t)rd.x * 256 + lane * 4);
        acc += bflo(ra.y)*bflo(ha.x) + bfhi(ra.y)*bfhi(ha.x)
             + bflo(ra.z)*bflo(ha.y) + bfhi(ra.z)*bfhi(ha.y);
        acc += bflo(rb.y)*bflo(hbv.x) + bfhi(rb.y)*bfhi(hbv.x)
             + bflo(rb.z)*bflo(hbv.y) + bfhi(rb.z)*bfhi(hbv.y);
        acc += bflo(rc.y)*bflo(hc.x) + bfhi(rc.y)*bfhi(hc.x)
             + bflo(rc.z)*bflo(hc.y) + bfhi(rc.z)*bfhi(hc.y);
        acc += bflo(rd.y)*bflo(hd.x) + bfhi(rd.y)*bfhi(hd.x)
             + bflo(rd.z)*bflo(hd.y) + bfhi(rd.z)*bfhi(hd.y);
    }
    for (; j < r1; ++j) {
        const uint4 ra = rec[j];
        const uint2 ha = *(const uint2*)(hb + (size_t)ra.x * 256 + lane * 4);
        acc += bflo(ra.y)*bflo(ha.x) + bfhi(ra.y)*bfhi(ha.x)
             + bflo(ra.z)*bflo(ha.y) + bfhi(ra.z)*bfhi(ha.y);
    }
    out[(size_t)v * OUT_F + lane] = acc + feat[(size_t)v * OUT_F + lane] + bias[lane];
}

extern "C" void kernel_launch(void* const* d_in, const int* in_sizes, int n_in,
                              void* d_out, int out_size, void* d_ws, size_t ws_size,
                              hipStream_t stream) {
    const float* feat      = (const float*)d_in[0];
    const float* pseudo    = (const float*)d_in[1];
    const int*   src       = (const int*)d_in[2];
    const int*   dst       = (const int*)d_in[3];
    const float* W_fc      = (const float*)d_in[4];
    const float* mu        = (const float*)d_in[5];
    const float* inv_sigma = (const float*)d_in[6];
    const float* bias      = (const float*)d_in[7];
    float* out = (float*)d_out;

    char* ws = (char*)d_ws;
    unsigned short* hb = (unsigned short*)ws;  ws += (size_t)N_NODES_C * 256 * 2;   // 51.2 MB
    uint2* g8          = (uint2*)ws;           ws += (size_t)N_EDGES_C * 8;         // 12.8 MB
    uint4* rec         = (uint4*)ws;           ws += (size_t)N_EDGES_C * 16;        // 25.6 MB
    int* cnt           = (int*)ws;             ws += (size_t)N_NODES_C * 4;
    int* row_start     = (int*)ws;             ws += (size_t)(N_NODES_C + 4) * 4;
    int* cursor        = (int*)ws;             ws += (size_t)N_NODES_C * 4;
    int* bsum          = (int*)ws;             ws += 512 * 4;

    hipMemsetAsync(cnt, 0, (size_t)N_NODES_C * 4, stream);
    fused1_kernel<<<EBLK + PB, 256, 0, stream>>>(
        src, dst, pseudo, mu, inv_sigma, cnt, g8, feat, W_fc, hb);
    scan1_kernel<<<NBLK, SCAN_BLK, 0, stream>>>(cnt, bsum);
    scan23_kernel<<<NBLK, SCAN_BLK, 0, stream>>>(cnt, bsum, row_start, cursor);
    scatter_kernel<<<EBLK, 256, 0, stream>>>(src, dst, g8, cursor, rec);
    gather_kernel<<<(N_NODES_C * 64 + 255) / 256, 256, 0, stream>>>(
        row_start, rec, hb, feat, bias, out, N_NODES_C);
}

// Round 6
// 661.618 us; speedup vs baseline: 1.0393x; 1.0393x over previous
//
#include <hip/hip_runtime.h>

#define N_NODES_C 100000
#define N_EDGES_C 1600000
#define IN_F 64
#define OUT_F 64
#define NK 4
#define SCAN_BLK 256
#define NBLK ((N_NODES_C + SCAN_BLK - 1) / SCAN_BLK)   // 391
#define EBLK (N_EDGES_C / 256)                         // 6250 exact
#define PROJ_GRID 2048                                 // even
#define NTILES (N_NODES_C / 4)                         // 25000

__device__ __forceinline__ unsigned int f2bf(float x) {
    unsigned int u = __float_as_uint(x);
    return (u + 0x7fffu + ((u >> 16) & 1u)) >> 16;
}
__device__ __forceinline__ float bflo(unsigned int u) { return __uint_as_float(u << 16); }
__device__ __forceinline__ float bfhi(unsigned int u) { return __uint_as_float(u & 0xffff0000u); }

// ---------------------------------------------------------------------------
// hist + gaussian weights, edge-parallel, fully coalesced
// ---------------------------------------------------------------------------
__global__ __launch_bounds__(256) void hist_gauss_kernel(
    const int* __restrict__ dst, const float* __restrict__ pseudo,
    const float* __restrict__ mu, const float* __restrict__ inv_sigma,
    int* __restrict__ cnt, uint2* __restrict__ g8)
{
    const int e = blockIdx.x * 256 + threadIdx.x;
    if (e >= N_EDGES_C) return;
    atomicAdd(&cnt[dst[e]], 1);
    const float p0 = pseudo[(size_t)e * 3 + 0];
    const float p1 = pseudo[(size_t)e * 3 + 1];
    const float p2 = pseudo[(size_t)e * 3 + 2];
    float g[NK];
    #pragma unroll
    for (int k = 0; k < NK; ++k) {
        const float d0 = p0 - mu[k*3+0], d1 = p1 - mu[k*3+1], d2 = p2 - mu[k*3+2];
        const float s0 = inv_sigma[k*3+0], s1 = inv_sigma[k*3+1], s2 = inv_sigma[k*3+2];
        const float ex = -0.5f * (d0*d0*s0*s0 + d1*d1*s1*s1 + d2*d2*s2*s2);
        g[k] = __expf(ex);
    }
    uint2 r;
    r.x = f2bf(g[0]) | (f2bf(g[1]) << 16);
    r.y = f2bf(g[2]) | (f2bf(g[3]) << 16);
    g8[e] = r;
}

// ---------------------------------------------------------------------------
// proj standalone: thread t handles col=(t>>1)+128*(bid&1), K-half h=t&1.
// 32 W floats in regs; feat read as broadcast float4 (L1); shfl combine.
// ---------------------------------------------------------------------------
__global__ __launch_bounds__(256) void proj_kernel(
    const float* __restrict__ feat, const float* __restrict__ W,
    unsigned short* __restrict__ hb)
{
    const int t = threadIdx.x;
    const int col = (t >> 1) + 128 * ((int)blockIdx.x & 1);
    const int h = t & 1;
    const int row = (col & 3) * 64 + (col >> 2);   // W_fc row for this col
    float4 wv[8];
    {
        const float4* W4 = reinterpret_cast<const float4*>(W + (size_t)row * IN_F + h * 32);
        #pragma unroll
        for (int i = 0; i < 8; ++i) wv[i] = W4[i];
    }
    for (int q = (int)blockIdx.x >> 1; q < NTILES; q += PROJ_GRID / 2) {
        const int n0 = q << 2;
        const float4* F = reinterpret_cast<const float4*>(feat + (size_t)n0 * IN_F + h * 32);
        float a0 = 0.f, a1 = 0.f, a2 = 0.f, a3 = 0.f;
        #pragma unroll
        for (int i0 = 0; i0 < 8; ++i0) {
            const float4 w = wv[i0];
            const float4 f0 = F[i0];
            const float4 f1 = F[i0 + 16];
            const float4 f2 = F[i0 + 32];
            const float4 f3 = F[i0 + 48];
            a0 = fmaf(f0.x,w.x, fmaf(f0.y,w.y, fmaf(f0.z,w.z, fmaf(f0.w,w.w, a0))));
            a1 = fmaf(f1.x,w.x, fmaf(f1.y,w.y, fmaf(f1.z,w.z, fmaf(f1.w,w.w, a1))));
            a2 = fmaf(f2.x,w.x, fmaf(f2.y,w.y, fmaf(f2.z,w.z, fmaf(f2.w,w.w, a2))));
            a3 = fmaf(f3.x,w.x, fmaf(f3.y,w.y, fmaf(f3.z,w.z, fmaf(f3.w,w.w, a3))));
        }
        a0 += __shfl_xor(a0, 1, 64);
        a1 += __shfl_xor(a1, 1, 64);
        a2 += __shfl_xor(a2, 1, 64);
        a3 += __shfl_xor(a3, 1, 64);
        const int na = h * 2;
        const float va = (h == 0) ? a0 : a2;
        const float vb = (h == 0) ? a1 : a3;
        hb[(size_t)(n0 + na + 0) * 256 + col] = (unsigned short)f2bf(va);
        hb[(size_t)(n0 + na + 1) * 256 + col] = (unsigned short)f2bf(vb);
    }
}

// ---------------------------------------------------------------------------
// scan1: per-block sums of cnt
// ---------------------------------------------------------------------------
__global__ __launch_bounds__(256) void scan1_kernel(
    const int* __restrict__ cnt, int* __restrict__ bsum)
{
    __shared__ int s[SCAN_BLK];
    int i = blockIdx.x * SCAN_BLK + threadIdx.x;
    int v = (i < N_NODES_C) ? cnt[i] : 0;
    s[threadIdx.x] = v; __syncthreads();
    for (int off = SCAN_BLK / 2; off > 0; off >>= 1) {
        if (threadIdx.x < off) s[threadIdx.x] += s[threadIdx.x + off];
        __syncthreads();
    }
    if (threadIdx.x == 0) bsum[blockIdx.x] = s[0];
}

// ---------------------------------------------------------------------------
// scan23: block-prefix over bsum + local exclusive scan -> row_start, cursor
// ---------------------------------------------------------------------------
__global__ __launch_bounds__(256) void scan23_kernel(
    const int* __restrict__ cnt, const int* __restrict__ bsum,
    int* __restrict__ row_start, int* __restrict__ cursor)
{
    __shared__ int pre[SCAN_BLK];
    __shared__ int s[SCAN_BLK];
    const int t = threadIdx.x;
    int p = 0;
    for (int i = t; i < (int)blockIdx.x; i += SCAN_BLK) p += bsum[i];
    pre[t] = p; __syncthreads();
    for (int off = SCAN_BLK / 2; off > 0; off >>= 1) {
        if (t < off) pre[t] += pre[t + off];
        __syncthreads();
    }
    const int boff = pre[0];
    const int i = blockIdx.x * SCAN_BLK + t;
    int v = (i < N_NODES_C) ? cnt[i] : 0;
    s[t] = v; __syncthreads();
    for (int off = 1; off < SCAN_BLK; off <<= 1) {
        int x = (t >= off) ? s[t - off] : 0;
        __syncthreads();
        s[t] += x;
        __syncthreads();
    }
    if (i < N_NODES_C) {
        int ex = s[t] - v + boff;
        row_start[i] = ex;
        cursor[i] = ex;
        if (i == N_NODES_C - 1) row_start[N_NODES_C] = ex + v;
    }
}

// ---------------------------------------------------------------------------
// scatter: coalesced reads, atomic pos, one 16B scattered record store
// ---------------------------------------------------------------------------
__global__ __launch_bounds__(256) void scatter_kernel(
    const int* __restrict__ src, const int* __restrict__ dst,
    const uint2* __restrict__ g8, int* __restrict__ cursor,
    uint4* __restrict__ rec)
{
    const int e = blockIdx.x * 256 + threadIdx.x;
    if (e >= N_EDGES_C) return;
    const int d = dst[e];
    const int s = src[e];
    const uint2 g = g8[e];
    const int pos = atomicAdd(&cursor[d], 1);
    uint4 r; r.x = (unsigned int)s; r.y = g.x; r.z = g.y; r.w = 0u;
    rec[pos] = r;
}

// ---------------------------------------------------------------------------
// gather: one wave per dst node, lane = output feature, unroll x4 for MLP.
// ---------------------------------------------------------------------------
__global__ __launch_bounds__(256) void gather_kernel(
    const int* __restrict__ row_start, const uint4* __restrict__ rec,
    const unsigned short* __restrict__ hb,
    const float* __restrict__ feat, const float* __restrict__ bias,
    float* __restrict__ out, int n_nodes)
{
    const int lane = threadIdx.x & 63;
    const int v = (blockIdx.x * 256 + threadIdx.x) >> 6;
    if (v >= n_nodes) return;
    const int r0 = row_start[v];
    const int r1 = row_start[v + 1];
    float acc = 0.f;
    int j = r0;
    for (; j + 4 <= r1; j += 4) {
        const uint4 ra = rec[j+0];
        const uint4 rb = rec[j+1];
        const uint4 rc = rec[j+2];
        const uint4 rd = rec[j+3];
        const uint2 ha = *(const uint2*)(hb + (size_t)ra.x * 256 + lane * 4);
        const uint2 hbv= *(const uint2*)(hb + (size_t)rb.x * 256 + lane * 4);
        const uint2 hc = *(const uint2*)(hb + (size_t)rc.x * 256 + lane * 4);
        const uint2 hd = *(const uint2*)(hb + (size_t)rd.x * 256 + lane * 4);
        acc += bflo(ra.y)*bflo(ha.x) + bfhi(ra.y)*bfhi(ha.x)
             + bflo(ra.z)*bflo(ha.y) + bfhi(ra.z)*bfhi(ha.y);
        acc += bflo(rb.y)*bflo(hbv.x) + bfhi(rb.y)*bfhi(hbv.x)
             + bflo(rb.z)*bflo(hbv.y) + bfhi(rb.z)*bfhi(hbv.y);
        acc += bflo(rc.y)*bflo(hc.x) + bfhi(rc.y)*bfhi(hc.x)
             + bflo(rc.z)*bflo(hc.y) + bfhi(rc.z)*bfhi(hc.y);
        acc += bflo(rd.y)*bflo(hd.x) + bfhi(rd.y)*bfhi(hd.x)
             + bflo(rd.z)*bflo(hd.y) + bfhi(rd.z)*bfhi(hd.y);
    }
    for (; j < r1; ++j) {
        const uint4 ra = rec[j];
        const uint2 ha = *(const uint2*)(hb + (size_t)ra.x * 256 + lane * 4);
        acc += bflo(ra.y)*bflo(ha.x) + bfhi(ra.y)*bfhi(ha.x)
             + bflo(ra.z)*bflo(ha.y) + bfhi(ra.z)*bfhi(ha.y);
    }
    out[(size_t)v * OUT_F + lane] = acc + feat[(size_t)v * OUT_F + lane] + bias[lane];
}

extern "C" void kernel_launch(void* const* d_in, const int* in_sizes, int n_in,
                              void* d_out, int out_size, void* d_ws, size_t ws_size,
                              hipStream_t stream) {
    const float* feat      = (const float*)d_in[0];
    const float* pseudo    = (const float*)d_in[1];
    const int*   src       = (const int*)d_in[2];
    const int*   dst       = (const int*)d_in[3];
    const float* W_fc      = (const float*)d_in[4];
    const float* mu        = (const float*)d_in[5];
    const float* inv_sigma = (const float*)d_in[6];
    const float* bias      = (const float*)d_in[7];
    float* out = (float*)d_out;

    char* ws = (char*)d_ws;
    unsigned short* hb = (unsigned short*)ws;  ws += (size_t)N_NODES_C * 256 * 2;   // 51.2 MB
    uint2* g8          = (uint2*)ws;           ws += (size_t)N_EDGES_C * 8;         // 12.8 MB
    uint4* rec         = (uint4*)ws;           ws += (size_t)N_EDGES_C * 16;        // 25.6 MB
    int* cnt           = (int*)ws;             ws += (size_t)N_NODES_C * 4;
    int* row_start     = (int*)ws;             ws += (size_t)(N_NODES_C + 4) * 4;
    int* cursor        = (int*)ws;             ws += (size_t)N_NODES_C * 4;
    int* bsum          = (int*)ws;             ws += 512 * 4;

    hipMemsetAsync(cnt, 0, (size_t)N_NODES_C * 4, stream);
    hist_gauss_kernel<<<EBLK, 256, 0, stream>>>(dst, pseudo, mu, inv_sigma, cnt, g8);
    proj_kernel<<<PROJ_GRID, 256, 0, stream>>>(feat, W_fc, hb);
    scan1_kernel<<<NBLK, SCAN_BLK, 0, stream>>>(cnt, bsum);
    scan23_kernel<<<NBLK, SCAN_BLK, 0, stream>>>(cnt, bsum, row_start, cursor);
    scatter_kernel<<<EBLK, 256, 0, stream>>>(src, dst, g8, cursor, rec);
    gather_kernel<<<(N_NODES_C * 64 + 255) / 256, 256, 0, stream>>>(
        row_start, rec, hb, feat, bias, out, N_NODES_C);
}

// Round 7
// 659.533 us; speedup vs baseline: 1.0426x; 1.0032x over previous
//
#include <hip/hip_runtime.h>

#define N_NODES_C 100000
#define N_EDGES_C 1600000
#define IN_F 64
#define OUT_F 64
#define NK 4
#define SCAN_BLK 256
#define NBLK ((N_NODES_C + SCAN_BLK - 1) / SCAN_BLK)   // 391
#define EBLK (N_EDGES_C / 256)                         // 6250 exact
#define PROJ_GRID 2048                                 // multiple of 4
#define NTILES (N_NODES_C / 4)                         // 25000

__device__ __forceinline__ unsigned int f2bf(float x) {
    unsigned int u = __float_as_uint(x);
    return (u + 0x7fffu + ((u >> 16) & 1u)) >> 16;
}
__device__ __forceinline__ float bflo(unsigned int u) { return __uint_as_float(u << 16); }
__device__ __forceinline__ float bfhi(unsigned int u) { return __uint_as_float(u & 0xffff0000u); }

// ---------------------------------------------------------------------------
// hist + gaussian weights, edge-parallel, fully coalesced
// ---------------------------------------------------------------------------
__global__ __launch_bounds__(256) void hist_gauss_kernel(
    const int* __restrict__ dst, const float* __restrict__ pseudo,
    const float* __restrict__ mu, const float* __restrict__ inv_sigma,
    int* __restrict__ cnt, uint2* __restrict__ g8)
{
    const int e = blockIdx.x * 256 + threadIdx.x;
    if (e >= N_EDGES_C) return;
    atomicAdd(&cnt[dst[e]], 1);
    const float p0 = pseudo[(size_t)e * 3 + 0];
    const float p1 = pseudo[(size_t)e * 3 + 1];
    const float p2 = pseudo[(size_t)e * 3 + 2];
    float g[NK];
    #pragma unroll
    for (int k = 0; k < NK; ++k) {
        const float d0 = p0 - mu[k*3+0], d1 = p1 - mu[k*3+1], d2 = p2 - mu[k*3+2];
        const float s0 = inv_sigma[k*3+0], s1 = inv_sigma[k*3+1], s2 = inv_sigma[k*3+2];
        const float ex = -0.5f * (d0*d0*s0*s0 + d1*d1*s1*s1 + d2*d2*s2*s2);
        g[k] = __expf(ex);
    }
    uint2 r;
    r.x = f2bf(g[0]) | (f2bf(g[1]) << 16);
    r.y = f2bf(g[2]) | (f2bf(g[3]) << 16);
    g8[e] = r;
}

// ---------------------------------------------------------------------------
// proj: K=64 dot split over 4 lanes (kq = t&3). Per thread only 16 W floats
// (loop-invariant, hoisted). colgroup fixed per block -> col = (bid&3)*64+(t>>2).
// 4 nodes per iteration; combine K-quarters with shfl_xor(1),(2); lane kq
// stores node n0+kq. VGPR need ~50; __launch_bounds__(256,4) caps at 128.
// ---------------------------------------------------------------------------
__global__ __launch_bounds__(256, 4) void proj_kernel(
    const float* __restrict__ feat, const float* __restrict__ W,
    unsigned short* __restrict__ hb)
{
    const int t  = threadIdx.x;
    const int kq = t & 3;                                  // K-quarter
    const int col = (((int)blockIdx.x & 3) << 6) + (t >> 2);
    const int row = (col & 3) * 64 + (col >> 2);           // W_fc row for this col
    float4 wv0, wv1, wv2, wv3;
    {
        const float4* W4 = reinterpret_cast<const float4*>(W + (size_t)row * IN_F + kq * 16);
        wv0 = W4[0]; wv1 = W4[1]; wv2 = W4[2]; wv3 = W4[3];
    }
    for (int q = (int)blockIdx.x >> 2; q < NTILES; q += (int)gridDim.x >> 2) {
        const int n0 = q << 2;
        // float4 base: (n0*64 + kq*16)/4 = n0*16 + kq*4 ; node r at +r*16
        const float4* F = reinterpret_cast<const float4*>(feat) + ((size_t)n0 * 16 + kq * 4);
        float acc[4];
        #pragma unroll
        for (int r = 0; r < 4; ++r) {
            const float4 f0 = F[r*16+0], f1 = F[r*16+1], f2 = F[r*16+2], f3 = F[r*16+3];
            float a;
            a = fmaf(f0.x,wv0.x, fmaf(f0.y,wv0.y, fmaf(f0.z,wv0.z, f0.w*wv0.w)));
            a = fmaf(f1.x,wv1.x, fmaf(f1.y,wv1.y, fmaf(f1.z,wv1.z, fmaf(f1.w,wv1.w, a))));
            a = fmaf(f2.x,wv2.x, fmaf(f2.y,wv2.y, fmaf(f2.z,wv2.z, fmaf(f2.w,wv2.w, a))));
            a = fmaf(f3.x,wv3.x, fmaf(f3.y,wv3.y, fmaf(f3.z,wv3.z, fmaf(f3.w,wv3.w, a))));
            acc[r] = a;
        }
        #pragma unroll
        for (int r = 0; r < 4; ++r) {
            acc[r] += __shfl_xor(acc[r], 1, 64);
            acc[r] += __shfl_xor(acc[r], 2, 64);
        }
        const float v = (kq == 0) ? acc[0] : (kq == 1) ? acc[1] : (kq == 2) ? acc[2] : acc[3];
        hb[(size_t)(n0 + kq) * 256 + col] = (unsigned short)f2bf(v);
    }
}

// ---------------------------------------------------------------------------
// scan1: per-block sums of cnt
// ---------------------------------------------------------------------------
__global__ __launch_bounds__(256) void scan1_kernel(
    const int* __restrict__ cnt, int* __restrict__ bsum)
{
    __shared__ int s[SCAN_BLK];
    int i = blockIdx.x * SCAN_BLK + threadIdx.x;
    int v = (i < N_NODES_C) ? cnt[i] : 0;
    s[threadIdx.x] = v; __syncthreads();
    for (int off = SCAN_BLK / 2; off > 0; off >>= 1) {
        if (threadIdx.x < off) s[threadIdx.x] += s[threadIdx.x + off];
        __syncthreads();
    }
    if (threadIdx.x == 0) bsum[blockIdx.x] = s[0];
}

// ---------------------------------------------------------------------------
// scan23: block-prefix over bsum + local exclusive scan -> row_start, cursor
// ---------------------------------------------------------------------------
__global__ __launch_bounds__(256) void scan23_kernel(
    const int* __restrict__ cnt, const int* __restrict__ bsum,
    int* __restrict__ row_start, int* __restrict__ cursor)
{
    __shared__ int pre[SCAN_BLK];
    __shared__ int s[SCAN_BLK];
    const int t = threadIdx.x;
    int p = 0;
    for (int i = t; i < (int)blockIdx.x; i += SCAN_BLK) p += bsum[i];
    pre[t] = p; __syncthreads();
    for (int off = SCAN_BLK / 2; off > 0; off >>= 1) {
        if (t < off) pre[t] += pre[t + off];
        __syncthreads();
    }
    const int boff = pre[0];
    const int i = blockIdx.x * SCAN_BLK + t;
    int v = (i < N_NODES_C) ? cnt[i] : 0;
    s[t] = v; __syncthreads();
    for (int off = 1; off < SCAN_BLK; off <<= 1) {
        int x = (t >= off) ? s[t - off] : 0;
        __syncthreads();
        s[t] += x;
        __syncthreads();
    }
    if (i < N_NODES_C) {
        int ex = s[t] - v + boff;
        row_start[i] = ex;
        cursor[i] = ex;
        if (i == N_NODES_C - 1) row_start[N_NODES_C] = ex + v;
    }
}

// ---------------------------------------------------------------------------
// scatter: coalesced reads, atomic pos, one 16B scattered record store
// ---------------------------------------------------------------------------
__global__ __launch_bounds__(256) void scatter_kernel(
    const int* __restrict__ src, const int* __restrict__ dst,
    const uint2* __restrict__ g8, int* __restrict__ cursor,
    uint4* __restrict__ rec)
{
    const int e = blockIdx.x * 256 + threadIdx.x;
    if (e >= N_EDGES_C) return;
    const int d = dst[e];
    const int s = src[e];
    const uint2 g = g8[e];
    const int pos = atomicAdd(&cursor[d], 1);
    uint4 r; r.x = (unsigned int)s; r.y = g.x; r.z = g.y; r.w = 0u;
    rec[pos] = r;
}

// ---------------------------------------------------------------------------
// gather: one wave per dst node, lane = output feature, unroll x4 for MLP.
// ---------------------------------------------------------------------------
__global__ __launch_bounds__(256) void gather_kernel(
    const int* __restrict__ row_start, const uint4* __restrict__ rec,
    const unsigned short* __restrict__ hb,
    const float* __restrict__ feat, const float* __restrict__ bias,
    float* __restrict__ out, int n_nodes)
{
    const int lane = threadIdx.x & 63;
    const int v = (blockIdx.x * 256 + threadIdx.x) >> 6;
    if (v >= n_nodes) return;
    const int r0 = row_start[v];
    const int r1 = row_start[v + 1];
    float acc = 0.f;
    int j = r0;
    for (; j + 4 <= r1; j += 4) {
        const uint4 ra = rec[j+0];
        const uint4 rb = rec[j+1];
        const uint4 rc = rec[j+2];
        const uint4 rd = rec[j+3];
        const uint2 ha = *(const uint2*)(hb + (size_t)ra.x * 256 + lane * 4);
        const uint2 hbv= *(const uint2*)(hb + (size_t)rb.x * 256 + lane * 4);
        const uint2 hc = *(const uint2*)(hb + (size_t)rc.x * 256 + lane * 4);
        const uint2 hd = *(const uint2*)(hb + (size_t)rd.x * 256 + lane * 4);
        acc += bflo(ra.y)*bflo(ha.x) + bfhi(ra.y)*bfhi(ha.x)
             + bflo(ra.z)*bflo(ha.y) + bfhi(ra.z)*bfhi(ha.y);
        acc += bflo(rb.y)*bflo(hbv.x) + bfhi(rb.y)*bfhi(hbv.x)
             + bflo(rb.z)*bflo(hbv.y) + bfhi(rb.z)*bfhi(hbv.y);
        acc += bflo(rc.y)*bflo(hc.x) + bfhi(rc.y)*bfhi(hc.x)
             + bflo(rc.z)*bflo(hc.y) + bfhi(rc.z)*bfhi(hc.y);
        acc += bflo(rd.y)*bflo(hd.x) + bfhi(rd.y)*bfhi(hd.x)
             + bflo(rd.z)*bflo(hd.y) + bfhi(rd.z)*bfhi(hd.y);
    }
    for (; j < r1; ++j) {
        const uint4 ra = rec[j];
        const uint2 ha = *(const uint2*)(hb + (size_t)ra.x * 256 + lane * 4);
        acc += bflo(ra.y)*bflo(ha.x) + bfhi(ra.y)*bfhi(ha.x)
             + bflo(ra.z)*bflo(ha.y) + bfhi(ra.z)*bfhi(ha.y);
    }
    out[(size_t)v * OUT_F + lane] = acc + feat[(size_t)v * OUT_F + lane] + bias[lane];
}

extern "C" void kernel_launch(void* const* d_in, const int* in_sizes, int n_in,
                              void* d_out, int out_size, void* d_ws, size_t ws_size,
                              hipStream_t stream) {
    const float* feat      = (const float*)d_in[0];
    const float* pseudo    = (const float*)d_in[1];
    const int*   src       = (const int*)d_in[2];
    const int*   dst       = (const int*)d_in[3];
    const float* W_fc      = (const float*)d_in[4];
    const float* mu        = (const float*)d_in[5];
    const float* inv_sigma = (const float*)d_in[6];
    const float* bias      = (const float*)d_in[7];
    float* out = (float*)d_out;

    char* ws = (char*)d_ws;
    unsigned short* hb = (unsigned short*)ws;  ws += (size_t)N_NODES_C * 256 * 2;   // 51.2 MB
    uint2* g8          = (uint2*)ws;           ws += (size_t)N_EDGES_C * 8;         // 12.8 MB
    uint4* rec         = (uint4*)ws;           ws += (size_t)N_EDGES_C * 16;        // 25.6 MB
    int* cnt           = (int*)ws;             ws += (size_t)N_NODES_C * 4;
    int* row_start     = (int*)ws;             ws += (size_t)(N_NODES_C + 4) * 4;
    int* cursor        = (int*)ws;             ws += (size_t)N_NODES_C * 4;
    int* bsum          = (int*)ws;             ws += 512 * 4;

    hipMemsetAsync(cnt, 0, (size_t)N_NODES_C * 4, stream);
    hist_gauss_kernel<<<EBLK, 256, 0, stream>>>(dst, pseudo, mu, inv_sigma, cnt, g8);
    proj_kernel<<<PROJ_GRID, 256, 0, stream>>>(feat, W_fc, hb);
    scan1_kernel<<<NBLK, SCAN_BLK, 0, stream>>>(cnt, bsum);
    scan23_kernel<<<NBLK, SCAN_BLK, 0, stream>>>(cnt, bsum, row_start, cursor);
    scatter_kernel<<<EBLK, 256, 0, stream>>>(src, dst, g8, cursor, rec);
    gather_kernel<<<(N_NODES_C * 64 + 255) / 256, 256, 0, stream>>>(
        row_start, rec, hb, feat, bias, out, N_NODES_C);
}

// Round 8
// 402.262 us; speedup vs baseline: 1.7094x; 1.6396x over previous
//
#include <hip/hip_runtime.h>

#define N_NODES_C 100000
#define N_EDGES_C 1600000
#define IN_F 64
#define OUT_F 64
#define NK 4
#define SCAN_BLK 256
#define NBLK ((N_NODES_C + SCAN_BLK - 1) / SCAN_BLK)   // 391
#define EBLK (N_EDGES_C / 256)                         // 6250 exact

__device__ __forceinline__ unsigned int f2bf(float x) {
    unsigned int u = __float_as_uint(x);
    return (u + 0x7fffu + ((u >> 16) & 1u)) >> 16;
}
__device__ __forceinline__ float bflo(unsigned int u) { return __uint_as_float(u << 16); }
__device__ __forceinline__ float bfhi(unsigned int u) { return __uint_as_float(u & 0xffff0000u); }

// ---------------------------------------------------------------------------
// hist + gaussian weights, edge-parallel, fully coalesced
// ---------------------------------------------------------------------------
__global__ __launch_bounds__(256) void hist_gauss_kernel(
    const int* __restrict__ dst, const float* __restrict__ pseudo,
    const float* __restrict__ mu, const float* __restrict__ inv_sigma,
    int* __restrict__ cnt, uint2* __restrict__ g8)
{
    const int e = blockIdx.x * 256 + threadIdx.x;
    if (e >= N_EDGES_C) return;
    atomicAdd(&cnt[dst[e]], 1);
    const float p0 = pseudo[(size_t)e * 3 + 0];
    const float p1 = pseudo[(size_t)e * 3 + 1];
    const float p2 = pseudo[(size_t)e * 3 + 2];
    float g[NK];
    #pragma unroll
    for (int k = 0; k < NK; ++k) {
        const float d0 = p0 - mu[k*3+0], d1 = p1 - mu[k*3+1], d2 = p2 - mu[k*3+2];
        const float s0 = inv_sigma[k*3+0], s1 = inv_sigma[k*3+1], s2 = inv_sigma[k*3+2];
        const float ex = -0.5f * (d0*d0*s0*s0 + d1*d1*s1*s1 + d2*d2*s2*s2);
        g[k] = __expf(ex);
    }
    uint2 r;
    r.x = f2bf(g[0]) | (f2bf(g[1]) << 16);
    r.y = f2bf(g[2]) | (f2bf(g[3]) << 16);
    g8[e] = r;
}

// ---------------------------------------------------------------------------
// proj (restored R2/R3 structure — empirically ~60-80us, no spill):
// thread t owns output col t = (o,k); scalar wreg[64] in regs; feat row
// broadcast via LDS; coalesced 2B stores hb[n*256+t].
// ---------------------------------------------------------------------------
__global__ __launch_bounds__(256, 2) void proj_kernel(
    const float* __restrict__ feat, const float* __restrict__ W,
    unsigned short* __restrict__ hb, int n_nodes)
{
    __shared__ float frow[IN_F];
    const int t = threadIdx.x;
    const int o = t >> 2;
    const int k = t & 3;
    float wreg[IN_F];
    {
        const float4* W4 = reinterpret_cast<const float4*>(W + (size_t)(k * OUT_F + o) * IN_F);
        #pragma unroll
        for (int i = 0; i < IN_F / 4; ++i) {
            float4 v = W4[i];
            wreg[4*i+0] = v.x; wreg[4*i+1] = v.y; wreg[4*i+2] = v.z; wreg[4*i+3] = v.w;
        }
    }
    for (int n = blockIdx.x; n < n_nodes; n += gridDim.x) {
        if (t < IN_F / 4) {
            float4 v = reinterpret_cast<const float4*>(feat + (size_t)n * IN_F)[t];
            frow[4*t+0] = v.x; frow[4*t+1] = v.y; frow[4*t+2] = v.z; frow[4*t+3] = v.w;
        }
        __syncthreads();
        float acc = 0.f;
        #pragma unroll
        for (int i = 0; i < IN_F; ++i) acc = fmaf(frow[i], wreg[i], acc);
        hb[(size_t)n * 256 + t] = (unsigned short)f2bf(acc);
        __syncthreads();
    }
}

// ---------------------------------------------------------------------------
// scan1: per-block sums of cnt
// ---------------------------------------------------------------------------
__global__ __launch_bounds__(256) void scan1_kernel(
    const int* __restrict__ cnt, int* __restrict__ bsum)
{
    __shared__ int s[SCAN_BLK];
    int i = blockIdx.x * SCAN_BLK + threadIdx.x;
    int v = (i < N_NODES_C) ? cnt[i] : 0;
    s[threadIdx.x] = v; __syncthreads();
    for (int off = SCAN_BLK / 2; off > 0; off >>= 1) {
        if (threadIdx.x < off) s[threadIdx.x] += s[threadIdx.x + off];
        __syncthreads();
    }
    if (threadIdx.x == 0) bsum[blockIdx.x] = s[0];
}

// ---------------------------------------------------------------------------
// scan23: block-prefix over bsum + local exclusive scan -> row_start, cursor
// ---------------------------------------------------------------------------
__global__ __launch_bounds__(256) void scan23_kernel(
    const int* __restrict__ cnt, const int* __restrict__ bsum,
    int* __restrict__ row_start, int* __restrict__ cursor)
{
    __shared__ int pre[SCAN_BLK];
    __shared__ int s[SCAN_BLK];
    const int t = threadIdx.x;
    int p = 0;
    for (int i = t; i < (int)blockIdx.x; i += SCAN_BLK) p += bsum[i];
    pre[t] = p; __syncthreads();
    for (int off = SCAN_BLK / 2; off > 0; off >>= 1) {
        if (t < off) pre[t] += pre[t + off];
        __syncthreads();
    }
    const int boff = pre[0];
    const int i = blockIdx.x * SCAN_BLK + t;
    int v = (i < N_NODES_C) ? cnt[i] : 0;
    s[t] = v; __syncthreads();
    for (int off = 1; off < SCAN_BLK; off <<= 1) {
        int x = (t >= off) ? s[t - off] : 0;
        __syncthreads();
        s[t] += x;
        __syncthreads();
    }
    if (i < N_NODES_C) {
        int ex = s[t] - v + boff;
        row_start[i] = ex;
        cursor[i] = ex;
        if (i == N_NODES_C - 1) row_start[N_NODES_C] = ex + v;
    }
}

// ---------------------------------------------------------------------------
// scatter: coalesced reads, atomic pos, one 16B scattered record store
// ---------------------------------------------------------------------------
__global__ __launch_bounds__(256) void scatter_kernel(
    const int* __restrict__ src, const int* __restrict__ dst,
    const uint2* __restrict__ g8, int* __restrict__ cursor,
    uint4* __restrict__ rec)
{
    const int e = blockIdx.x * 256 + threadIdx.x;
    if (e >= N_EDGES_C) return;
    const int d = dst[e];
    const int s = src[e];
    const uint2 g = g8[e];
    const int pos = atomicAdd(&cursor[d], 1);
    uint4 r; r.x = (unsigned int)s; r.y = g.x; r.z = g.y; r.w = 0u;
    rec[pos] = r;
}

// ---------------------------------------------------------------------------
// gather: one wave per dst node, lane = output feature, unroll x4 for MLP.
// ---------------------------------------------------------------------------
__global__ __launch_bounds__(256) void gather_kernel(
    const int* __restrict__ row_start, const uint4* __restrict__ rec,
    const unsigned short* __restrict__ hb,
    const float* __restrict__ feat, const float* __restrict__ bias,
    float* __restrict__ out, int n_nodes)
{
    const int lane = threadIdx.x & 63;
    const int v = (blockIdx.x * 256 + threadIdx.x) >> 6;
    if (v >= n_nodes) return;
    const int r0 = row_start[v];
    const int r1 = row_start[v + 1];
    float acc = 0.f;
    int j = r0;
    for (; j + 4 <= r1; j += 4) {
        const uint4 ra = rec[j+0];
        const uint4 rb = rec[j+1];
        const uint4 rc = rec[j+2];
        const uint4 rd = rec[j+3];
        const uint2 ha = *(const uint2*)(hb + (size_t)ra.x * 256 + lane * 4);
        const uint2 hbv= *(const uint2*)(hb + (size_t)rb.x * 256 + lane * 4);
        const uint2 hc = *(const uint2*)(hb + (size_t)rc.x * 256 + lane * 4);
        const uint2 hd = *(const uint2*)(hb + (size_t)rd.x * 256 + lane * 4);
        acc += bflo(ra.y)*bflo(ha.x) + bfhi(ra.y)*bfhi(ha.x)
             + bflo(ra.z)*bflo(ha.y) + bfhi(ra.z)*bfhi(ha.y);
        acc += bflo(rb.y)*bflo(hbv.x) + bfhi(rb.y)*bfhi(hbv.x)
             + bflo(rb.z)*bflo(hbv.y) + bfhi(rb.z)*bfhi(hbv.y);
        acc += bflo(rc.y)*bflo(hc.x) + bfhi(rc.y)*bfhi(hc.x)
             + bflo(rc.z)*bflo(hc.y) + bfhi(rc.z)*bfhi(hc.y);
        acc += bflo(rd.y)*bflo(hd.x) + bfhi(rd.y)*bfhi(hd.x)
             + bflo(rd.z)*bflo(hd.y) + bfhi(rd.z)*bfhi(hd.y);
    }
    for (; j < r1; ++j) {
        const uint4 ra = rec[j];
        const uint2 ha = *(const uint2*)(hb + (size_t)ra.x * 256 + lane * 4);
        acc += bflo(ra.y)*bflo(ha.x) + bfhi(ra.y)*bfhi(ha.x)
             + bflo(ra.z)*bflo(ha.y) + bfhi(ra.z)*bfhi(ha.y);
    }
    out[(size_t)v * OUT_F + lane] = acc + feat[(size_t)v * OUT_F + lane] + bias[lane];
}

extern "C" void kernel_launch(void* const* d_in, const int* in_sizes, int n_in,
                              void* d_out, int out_size, void* d_ws, size_t ws_size,
                              hipStream_t stream) {
    const float* feat      = (const float*)d_in[0];
    const float* pseudo    = (const float*)d_in[1];
    const int*   src       = (const int*)d_in[2];
    const int*   dst       = (const int*)d_in[3];
    const float* W_fc      = (const float*)d_in[4];
    const float* mu        = (const float*)d_in[5];
    const float* inv_sigma = (const float*)d_in[6];
    const float* bias      = (const float*)d_in[7];
    float* out = (float*)d_out;

    char* ws = (char*)d_ws;
    unsigned short* hb = (unsigned short*)ws;  ws += (size_t)N_NODES_C * 256 * 2;   // 51.2 MB
    uint2* g8          = (uint2*)ws;           ws += (size_t)N_EDGES_C * 8;         // 12.8 MB
    uint4* rec         = (uint4*)ws;           ws += (size_t)N_EDGES_C * 16;        // 25.6 MB
    int* cnt           = (int*)ws;             ws += (size_t)N_NODES_C * 4;
    int* row_start     = (int*)ws;             ws += (size_t)(N_NODES_C + 4) * 4;
    int* cursor        = (int*)ws;             ws += (size_t)N_NODES_C * 4;
    int* bsum          = (int*)ws;             ws += 512 * 4;

    hipMemsetAsync(cnt, 0, (size_t)N_NODES_C * 4, stream);
    hist_gauss_kernel<<<EBLK, 256, 0, stream>>>(dst, pseudo, mu, inv_sigma, cnt, g8);
    proj_kernel<<<2048, 256, 0, stream>>>(feat, W_fc, hb, N_NODES_C);
    scan1_kernel<<<NBLK, SCAN_BLK, 0, stream>>>(cnt, bsum);
    scan23_kernel<<<NBLK, SCAN_BLK, 0, stream>>>(cnt, bsum, row_start, cursor);
    scatter_kernel<<<EBLK, 256, 0, stream>>>(src, dst, g8, cursor, rec);
    gather_kernel<<<(N_NODES_C * 64 + 255) / 256, 256, 0, stream>>>(
        row_start, rec, hb, feat, bias, out, N_NODES_C);
}